// Round 1
// baseline (1353.737 us; speedup 1.0000x reference)
//
#include <hip/hip_runtime.h>
#include <math.h>

#define NUM_HEADS 32
#define HEAD_DIM 128
#define QRANK 1536
#define BSZ 8
#define SEQ 4096

// ---------------------------------------------------------------------------
// Kernel A: q[b][n] = hidden[b][:] @ W[:, n] + bias[n]
// 64 blocks x 256 threads. Each block owns 64 columns (n), k split 4-way.
// W reads: each wave = one k-slice, 64 lanes = 64 consecutive n -> coalesced.
// ---------------------------------------------------------------------------
__global__ __launch_bounds__(256) void qproj_kernel(
    const float* __restrict__ hq,   // [8][1536]
    const float* __restrict__ Wq,   // [1536][4096]
    const float* __restrict__ bq,   // [4096]
    float* __restrict__ qout)       // [8][4096]
{
    __shared__ float lh[BSZ * QRANK];   // 48 KB
    __shared__ float red[BSZ][4][64];   // 8 KB
    const int t = threadIdx.x;
    for (int i = t; i < BSZ * QRANK; i += 256) lh[i] = hq[i];
    __syncthreads();

    const int nl = t & 63;          // column within block
    const int ks = t >> 6;          // k-slice 0..3 (== wave id)
    const int n  = blockIdx.x * 64 + nl;

    float acc[BSZ];
#pragma unroll
    for (int b = 0; b < BSZ; ++b) acc[b] = 0.f;

    const int k0 = ks * (QRANK / 4);
    const int k1 = k0 + (QRANK / 4);
    for (int k = k0; k < k1; ++k) {
        float wv = Wq[(size_t)k * 4096 + n];
#pragma unroll
        for (int b = 0; b < BSZ; ++b) acc[b] += lh[b * QRANK + k] * wv;
    }
#pragma unroll
    for (int b = 0; b < BSZ; ++b) red[b][ks][nl] = acc[b];
    __syncthreads();

    if (ks == 0) {
#pragma unroll
        for (int b = 0; b < BSZ; ++b) {
            float s = red[b][0][nl] + red[b][1][nl] + red[b][2][nl] + red[b][3][nl]
                    + bq[n];
            qout[b * 4096 + n] = s;
        }
    }
}

// ---------------------------------------------------------------------------
// Kernel B: per (b,h): scores = q . K, softmax, out = P . V
// 256 blocks (one per (b,h)), 1024 threads = 16 waves.
// Wave w owns rows [w*256, (w+1)*256). Each iteration a half-wave (32 lanes)
// processes one row with float4 loads (32*4 = 128 floats = full head dim).
// All 4096 scores live in LDS -> plain two-pass softmax, no online rescale.
// ---------------------------------------------------------------------------
__global__ __launch_bounds__(1024) void attn_kernel(
    const float* __restrict__ kv,   // [8][4096][32][256]  (K | V per row)
    const float* __restrict__ q,    // [8][4096]
    float* __restrict__ out)        // [8][4096]
{
    __shared__ float  sc[SEQ];            // 16 KB  scores -> probs
    __shared__ float4 ored[16][2][32];    // 16 KB  per-(wave,half) partial O
    __shared__ float  wmaxr[16];
    __shared__ float  wsumr[16];

    const int b    = blockIdx.x >> 5;   // 0..7
    const int h    = blockIdx.x & 31;   // 0..31
    const int tid  = threadIdx.x;
    const int w    = tid >> 6;          // wave 0..15
    const int lane = tid & 63;
    const int sub  = lane & 31;         // lane within half-wave
    const int half = lane >> 5;         // 0/1

    // Per-lane q fragment: q[b][h*128 + 4*sub .. +3] (constant across rows)
    const float4 qf = *(const float4*)(q + (size_t)b * 4096 + h * 128 + 4 * sub);

    const float4* kv4 = (const float4*)kv;
    // float4 index of row r, channel-offset o4: (b*4096 + r)*2048 + h*64 + o4
    const long hb = (long)h * 64;

    // ---- pass 1: scores ----
    for (int it = 0; it < 128; ++it) {
        const int  row = w * 256 + it * 2 + half;
        const long idx = (long)(b * SEQ + row) * 2048 + hb + sub;   // K half
        const float4 kf = kv4[idx];
        float p = qf.x * kf.x + qf.y * kf.y + qf.z * kf.z + qf.w * kf.w;
        p += __shfl_xor(p, 1);
        p += __shfl_xor(p, 2);
        p += __shfl_xor(p, 4);
        p += __shfl_xor(p, 8);
        p += __shfl_xor(p, 16);
        if (sub == 0) sc[row] = p;
    }
    __syncthreads();

    // ---- block max ----
    float lm = -INFINITY;
    for (int i = tid; i < SEQ; i += 1024) lm = fmaxf(lm, sc[i]);
    lm = fmaxf(lm, __shfl_xor(lm, 1));
    lm = fmaxf(lm, __shfl_xor(lm, 2));
    lm = fmaxf(lm, __shfl_xor(lm, 4));
    lm = fmaxf(lm, __shfl_xor(lm, 8));
    lm = fmaxf(lm, __shfl_xor(lm, 16));
    lm = fmaxf(lm, __shfl_xor(lm, 32));
    if (lane == 0) wmaxr[w] = lm;
    __syncthreads();
    float m = wmaxr[0];
#pragma unroll
    for (int i = 1; i < 16; ++i) m = fmaxf(m, wmaxr[i]);

    // ---- exp + sum ----
    float ls = 0.f;
    for (int i = tid; i < SEQ; i += 1024) {
        float p = __expf(sc[i] - m);
        sc[i] = p;
        ls += p;
    }
    ls += __shfl_xor(ls, 1);
    ls += __shfl_xor(ls, 2);
    ls += __shfl_xor(ls, 4);
    ls += __shfl_xor(ls, 8);
    ls += __shfl_xor(ls, 16);
    ls += __shfl_xor(ls, 32);
    if (lane == 0) wsumr[w] = ls;
    __syncthreads();
    float l = 0.f;
#pragma unroll
    for (int i = 0; i < 16; ++i) l += wsumr[i];
    const float invl = 1.f / l;

    // ---- pass 2: O = P . V ----
    float4 acc = make_float4(0.f, 0.f, 0.f, 0.f);
    for (int it = 0; it < 128; ++it) {
        const int  row = w * 256 + it * 2 + half;
        const long idx = (long)(b * SEQ + row) * 2048 + hb + 32 + sub; // V half
        const float4 vf = kv4[idx];
        const float p = sc[row];
        acc.x += p * vf.x;
        acc.y += p * vf.y;
        acc.z += p * vf.z;
        acc.w += p * vf.w;
    }
    ored[w][half][sub] = acc;
    __syncthreads();

    // ---- combine 32 partials, scale, store ----
    if (tid < 128) {
        const float* of = (const float*)ored;   // viewed as [32][128]
        float s = 0.f;
#pragma unroll
        for (int i = 0; i < 32; ++i) s += of[i * 128 + tid];
        out[(size_t)b * 4096 + h * 128 + tid] = s * invl;
    }
}

extern "C" void kernel_launch(void* const* d_in, const int* in_sizes, int n_in,
                              void* d_out, int out_size, void* d_ws, size_t ws_size,
                              hipStream_t stream) {
    const float* hq = (const float*)d_in[0];   // [8][1536]
    const float* kv = (const float*)d_in[1];   // [8][4096][32][256]
    const float* Wq = (const float*)d_in[2];   // [1536][4096]
    const float* bq = (const float*)d_in[3];   // [4096]
    float* outp = (float*)d_out;               // [8][4096]
    float* qbuf = (float*)d_ws;                // 8*4096 floats = 128 KB scratch

    qproj_kernel<<<64, 256, 0, stream>>>(hq, Wq, bq, qbuf);
    attn_kernel<<<BSZ * NUM_HEADS, 1024, 0, stream>>>(kv, qbuf, outp);
}